// Round 3
// baseline (1738.747 us; speedup 1.0000x reference)
//
#include <hip/hip_runtime.h>
#include <math.h>

// Problem constants
#define BQ     1024
#define D      256
#define NTRAIN 200000
#define CCLS   1000
#define KTOP   20
#define KSEL   24          // order statistic used for the filter threshold
#define TEMPF  20.0f
#define EPSV   1e-8f

// GEMM tiling
#define NSEG    64         // segments; 64*3125 = 200000 exactly
#define SEGROWS 3125
#define SEGT    49         // ceil(3125/64) tiles of 64 rows
#define TGLOB   (NSEG * SEGT)   // 3136 tile slots per query
#define QTB     64         // queries per block (16 per wave)
#define CAP     256        // emission capacity per query (expected ~40)

typedef __attribute__((ext_vector_type(8))) short bf16x8;  // 8 bf16 = 4 VGPR
typedef __attribute__((ext_vector_type(4))) float f32x4;

static __device__ __forceinline__ unsigned short f2bf(float f) {
  unsigned int u = __float_as_uint(f);
  u += 0x7FFFu + ((u >> 16) & 1u);     // RTNE
  return (unsigned short)(u >> 16);
}

// ---------------------------------------------------------------------------
// Kernel 1: qf = l2_normalize((x - mean) * inv_std) (fp32); qb = bf16(qf)
// ---------------------------------------------------------------------------
__global__ void prep_q(const float* __restrict__ x, const float* __restrict__ mean,
                       const float* __restrict__ inv_std,
                       float* __restrict__ qf, unsigned short* __restrict__ qb) {
  int row = blockIdx.x;
  int t = threadIdx.x;
  float v = (x[row * D + t] - mean[t]) * inv_std[t];
  float s = v * v;
  #pragma unroll
  for (int off = 32; off; off >>= 1) s += __shfl_down(s, off);
  __shared__ float red[4];
  if ((t & 63) == 0) red[t >> 6] = s;
  __syncthreads();
  float tot = red[0] + red[1] + red[2] + red[3];
  float scale = 1.0f / fmaxf(sqrtf(tot), EPSV);
  float qv = v * scale;
  qf[row * D + t] = qv;
  qb[row * D + t] = f2bf(qv);
}

// ---------------------------------------------------------------------------
// Kernel 2: txb[n][k] = bf16(train_x[n][k] * rnorm[n]); rnorm saved (fp32)
// ---------------------------------------------------------------------------
__global__ void bank_prep(const float* __restrict__ tx,
                          unsigned short* __restrict__ txb, float* __restrict__ rnorm) {
  int lane = threadIdx.x & 63;
  int row = blockIdx.x * 4 + (threadIdx.x >> 6);
  const float4* p = reinterpret_cast<const float4*>(tx + (size_t)row * D);
  float4 a = p[lane];
  float s = a.x * a.x + a.y * a.y + a.z * a.z + a.w * a.w;
  #pragma unroll
  for (int off = 32; off; off >>= 1) s += __shfl_xor(s, off);
  float rn = 1.0f / fmaxf(sqrtf(s), EPSV);
  if (lane == 0) rnorm[row] = rn;
  ushort4 us;
  us.x = f2bf(a.x * rn); us.y = f2bf(a.y * rn);
  us.z = f2bf(a.z * rn); us.w = f2bf(a.w * rn);
  *reinterpret_cast<ushort4*>(txb + (size_t)row * D + lane * 4) = us;
}

// ---------------------------------------------------------------------------
// Kernel 3 (pass A): swapped-operand MFMA GEMM; emit per-(query, 64-row tile)
// max only. mfma(train, query): D[row=train(lane>>4)*4+r, col=query(lane&15)]
// -> each lane owns 1 query x 16 train rows per tile. No LDS, no barriers.
// grid 1024 = 16 q-tiles x 64 segments (swizzle: one segment's q-tiles on one XCD)
// ---------------------------------------------------------------------------
__global__ __launch_bounds__(256, 4)
void knn_passA(const unsigned short* __restrict__ qb, const unsigned short* __restrict__ txb,
               float* __restrict__ tmax) {
  int t = threadIdx.x, lane = t & 63, w = t >> 6;
  int c = lane & 15, g = lane >> 4;
  int b = blockIdx.x;
  int seg = (b & 7) * 8 + ((b >> 3) & 7);
  int qt  = b >> 6;
  int qrow = qt * QTB + w * 16 + c;           // this lane's query

  bf16x8 qfr[8];                               // B operand: col=c, k=g*8 (+ks*32)
  #pragma unroll
  for (int ks = 0; ks < 8; ++ks)
    qfr[ks] = *reinterpret_cast<const bf16x8*>(qb + (size_t)qrow * D + ks * 32 + g * 8);

  int nseg0 = seg * SEGROWS;
  int nsegEnd = nseg0 + SEGROWS;

  for (int tile = 0; tile < SEGT; ++tile) {
    int nbase = nseg0 + tile * 64;
    const unsigned short* tp[4];
    #pragma unroll
    for (int nf = 0; nf < 4; ++nf) {
      int row = nbase + nf * 16 + c;
      row = (row < nsegEnd) ? row : (nsegEnd - 1);   // clamp dup stays in same tile -> tile-max exact
      tp[nf] = txb + (size_t)row * D + g * 8;
    }
    f32x4 acc[4];
    #pragma unroll
    for (int nf = 0; nf < 4; ++nf) acc[nf] = (f32x4){0.f, 0.f, 0.f, 0.f};
    #pragma unroll
    for (int ks = 0; ks < 8; ++ks) {
      bf16x8 tfr[4];
      #pragma unroll
      for (int nf = 0; nf < 4; ++nf)
        tfr[nf] = *reinterpret_cast<const bf16x8*>(tp[nf] + ks * 32);
      #pragma unroll
      for (int nf = 0; nf < 4; ++nf)
        acc[nf] = __builtin_amdgcn_mfma_f32_16x16x32_bf16(tfr[nf], qfr[ks], acc[nf], 0, 0, 0);
    }
    // per-lane max over 16 rows, then max across the 4 g-lanes sharing query c
    float m0 = fmaxf(fmaxf(acc[0][0], acc[0][1]), fmaxf(acc[0][2], acc[0][3]));
    float m1 = fmaxf(fmaxf(acc[1][0], acc[1][1]), fmaxf(acc[1][2], acc[1][3]));
    float m2 = fmaxf(fmaxf(acc[2][0], acc[2][1]), fmaxf(acc[2][2], acc[2][3]));
    float m3 = fmaxf(fmaxf(acc[3][0], acc[3][1]), fmaxf(acc[3][2], acc[3][3]));
    float mx = fmaxf(fmaxf(m0, m1), fmaxf(m2, m3));
    mx = fmaxf(mx, __shfl_xor(mx, 16));
    mx = fmaxf(mx, __shfl_xor(mx, 32));
    if (g == 0) tmax[(size_t)(seg * SEGT + tile) * BQ + qrow] = mx;   // 16 lanes -> 64B coalesced
  }
}

// ---------------------------------------------------------------------------
// Kernel 4: tau[q] = 24th-largest of q's 3136 tile-maxes (exact order stat).
// Guarantee: >=24 elements have sim >= tau[q]  =>  bf16 top-24 all pass filter.
// ---------------------------------------------------------------------------
__global__ void sel_tau(const float* __restrict__ tmax, float* __restrict__ tau) {
  __shared__ float sv[4]; __shared__ int sj[4];
  __shared__ float sbv;   __shared__ int sbj;
  int q = blockIdx.x, t = threadIdx.x, lane = t & 63, w = t >> 6;
  float v[13];
  #pragma unroll
  for (int i = 0; i < 13; ++i) {
    int jj = i * 256 + t;
    v[i] = (jj < TGLOB) ? tmax[(size_t)jj * BQ + q] : -INFINITY;
  }
  float last = 0.f;
  for (int it = 0; it < KSEL; ++it) {
    float bv = -INFINITY; int bj = 0x7fffffff;
    #pragma unroll
    for (int i = 0; i < 13; ++i)
      if (v[i] > bv) { bv = v[i]; bj = i * 256 + t; }   // ties: smaller slot wins
    #pragma unroll
    for (int off = 32; off; off >>= 1) {
      float ov = __shfl_xor(bv, off); int oj = __shfl_xor(bj, off);
      if (ov > bv || (ov == bv && oj < bj)) { bv = ov; bj = oj; }
    }
    if (lane == 0) { sv[w] = bv; sj[w] = bj; }
    __syncthreads();
    if (t == 0) {
      float BV = sv[0]; int BJ = sj[0];
      #pragma unroll
      for (int k = 1; k < 4; ++k)
        if (sv[k] > BV || (sv[k] == BV && sj[k] < BJ)) { BV = sv[k]; BJ = sj[k]; }
      sbv = BV; sbj = BJ;
    }
    __syncthreads();
    float BV = sbv; int BJ = sbj;
    #pragma unroll
    for (int i = 0; i < 13; ++i)
      if (i * 256 + t == BJ) v[i] = -INFINITY;          // disable exactly one
    last = BV;
    __syncthreads();
  }
  if (t == 0) tau[q] = last;
}

// ---------------------------------------------------------------------------
// Kernel 5 (pass B): identical GEMM (bitwise-same sims); emit train index for
// every sim >= tau[q]. Emission is rare (~1.3% of slots at wave level).
// ---------------------------------------------------------------------------
__global__ __launch_bounds__(256, 4)
void knn_passB(const unsigned short* __restrict__ qb, const unsigned short* __restrict__ txb,
               const float* __restrict__ tau, int* __restrict__ cnt, int* __restrict__ lists) {
  int t = threadIdx.x, lane = t & 63, w = t >> 6;
  int c = lane & 15, g = lane >> 4;
  int b = blockIdx.x;
  int seg = (b & 7) * 8 + ((b >> 3) & 7);
  int qt  = b >> 6;
  int qrow = qt * QTB + w * 16 + c;

  bf16x8 qfr[8];
  #pragma unroll
  for (int ks = 0; ks < 8; ++ks)
    qfr[ks] = *reinterpret_cast<const bf16x8*>(qb + (size_t)qrow * D + ks * 32 + g * 8);
  float tq = tau[qrow];

  int nseg0 = seg * SEGROWS;
  int nsegEnd = nseg0 + SEGROWS;

  for (int tile = 0; tile < SEGT; ++tile) {
    int nbase = nseg0 + tile * 64;
    const unsigned short* tp[4];
    #pragma unroll
    for (int nf = 0; nf < 4; ++nf) {
      int row = nbase + nf * 16 + c;
      row = (row < nsegEnd) ? row : (nsegEnd - 1);
      tp[nf] = txb + (size_t)row * D + g * 8;
    }
    f32x4 acc[4];
    #pragma unroll
    for (int nf = 0; nf < 4; ++nf) acc[nf] = (f32x4){0.f, 0.f, 0.f, 0.f};
    #pragma unroll
    for (int ks = 0; ks < 8; ++ks) {
      bf16x8 tfr[4];
      #pragma unroll
      for (int nf = 0; nf < 4; ++nf)
        tfr[nf] = *reinterpret_cast<const bf16x8*>(tp[nf] + ks * 32);
      #pragma unroll
      for (int nf = 0; nf < 4; ++nf)
        acc[nf] = __builtin_amdgcn_mfma_f32_16x16x32_bf16(tfr[nf], qfr[ks], acc[nf], 0, 0, 0);
    }
    #pragma unroll
    for (int nf = 0; nf < 4; ++nf) {
      #pragma unroll
      for (int r = 0; r < 4; ++r) {
        int n = nbase + nf * 16 + g * 4 + r;            // unclamped: guards dup emission
        float v = acc[nf][r];
        if (n < nsegEnd && v >= tq) {
          int pos = atomicAdd(&cnt[qrow], 1);
          if (pos < CAP) lists[(size_t)qrow * CAP + pos] = n;
        }
      }
    }
  }
}

// ---------------------------------------------------------------------------
// Kernel 6: fp32-rescore all emissions, exact top-20 (val desc, idx asc),
// softmax(*20), scatter by label, write row.
// ---------------------------------------------------------------------------
__global__ void final_sel(const int* __restrict__ cnt, const int* __restrict__ lists,
                          const float* __restrict__ qf, const float* __restrict__ tx,
                          const float* __restrict__ rnorm, const int* __restrict__ train_y,
                          float* __restrict__ out) {
  __shared__ float qs[D];
  __shared__ float rv[CAP]; __shared__ int ri[CAP];
  __shared__ float sv[4];  __shared__ int sj[4];
  __shared__ float sbv;    __shared__ int sbj;
  __shared__ float ordv[KTOP]; __shared__ int ordi[KTOP];
  __shared__ float outrow[CCLS];
  int q = blockIdx.x, t = threadIdx.x, lane = t & 63, w = t >> 6;

  qs[t] = qf[q * D + t];
  for (int j = t; j < CCLS; j += 256) outrow[j] = 0.f;
  int m = cnt[q]; if (m > CAP) m = CAP;      // m >= 24 guaranteed by construction
  __syncthreads();

  // rescore: one wave per candidate, round-robin
  for (int k = w; k < m; k += 4) {
    int idx = lists[(size_t)q * CAP + k];
    float4 tv = reinterpret_cast<const float4*>(tx + (size_t)idx * D)[lane];
    float4 qv = *reinterpret_cast<const float4*>(&qs[lane * 4]);
    float s = tv.x * qv.x + tv.y * qv.y + tv.z * qv.z + tv.w * qv.w;
    #pragma unroll
    for (int off = 32; off; off >>= 1) s += __shfl_xor(s, off);
    if (lane == 0) { rv[k] = s * rnorm[idx]; ri[k] = idx; }
  }
  __syncthreads();

  // 20 rounds of extract-best keyed (value desc, train idx asc)
  float v0 = (t < m) ? rv[t] : -INFINITY;
  int   i0 = (t < m) ? ri[t] : 0x7fffffff;
  for (int it = 0; it < KTOP; ++it) {
    float bv = v0; int bj = i0;
    #pragma unroll
    for (int off = 32; off; off >>= 1) {
      float ov = __shfl_xor(bv, off); int oj = __shfl_xor(bj, off);
      if (ov > bv || (ov == bv && oj < bj)) { bv = ov; bj = oj; }
    }
    if (lane == 0) { sv[w] = bv; sj[w] = bj; }
    __syncthreads();
    if (t == 0) {
      float BV = sv[0]; int BJ = sj[0];
      #pragma unroll
      for (int k = 1; k < 4; ++k)
        if (sv[k] > BV || (sv[k] == BV && sj[k] < BJ)) { BV = sv[k]; BJ = sj[k]; }
      sbv = BV; sbj = BJ; ordv[it] = BV; ordi[it] = BJ;
    }
    __syncthreads();
    if (v0 == sbv && i0 == sbj) v0 = -INFINITY;   // indices unique -> exactly one
    __syncthreads();
  }

  if (w == 0) {
    float e = (lane < KTOP) ? expf((ordv[lane] - ordv[0]) * TEMPF) : 0.f;
    float ssum = e;
    #pragma unroll
    for (int off = 32; off; off >>= 1) ssum += __shfl_xor(ssum, off);
    if (lane < KTOP) atomicAdd(&outrow[train_y[ordi[lane]]], e / ssum);
  }
  __syncthreads();
  if (t < 250) reinterpret_cast<float4*>(out)[q * 250 + t] =
      reinterpret_cast<const float4*>(outrow)[t];
}

// ---------------------------------------------------------------------------
extern "C" void kernel_launch(void* const* d_in, const int* in_sizes, int n_in,
                              void* d_out, int out_size, void* d_ws, size_t ws_size,
                              hipStream_t stream) {
  const float* x       = (const float*)d_in[0];
  const float* mean    = (const float*)d_in[1];
  const float* inv_std = (const float*)d_in[2];
  const float* train_x = (const float*)d_in[3];
  const int*   train_y = (const int*)d_in[4];
  float* out = (float*)d_out;

  // workspace carve (~118.7 MB)
  char* wp = (char*)d_ws;
  float*          qf    = (float*)wp;          wp += (size_t)BQ * D * 4;          // 1.05 MB
  unsigned short* qb    = (unsigned short*)wp; wp += (size_t)BQ * D * 2;          // 0.52 MB
  float*          rnorm = (float*)wp;          wp += (size_t)NTRAIN * 4;          // 0.80 MB
  unsigned short* txb   = (unsigned short*)wp; wp += (size_t)NTRAIN * D * 2;      // 102.4 MB
  float*          tmax  = (float*)wp;          wp += (size_t)TGLOB * BQ * 4;      // 12.85 MB
  float*          tau   = (float*)wp;          wp += (size_t)BQ * 4;              // 4 KB
  int*            cnt   = (int*)wp;            wp += (size_t)BQ * 4;              // 4 KB
  int*            lists = (int*)wp;                                               // 1.05 MB

  prep_q   <<<BQ, 256, 0, stream>>>(x, mean, inv_std, qf, qb);
  bank_prep<<<NTRAIN / 4, 256, 0, stream>>>(train_x, txb, rnorm);
  knn_passA<<<16 * NSEG, 256, 0, stream>>>(qb, txb, tmax);
  sel_tau  <<<BQ, 256, 0, stream>>>(tmax, tau);
  hipMemsetAsync(cnt, 0, (size_t)BQ * 4, stream);
  knn_passB<<<16 * NSEG, 256, 0, stream>>>(qb, txb, tau, cnt, lists);
  final_sel<<<BQ, 256, 0, stream>>>(cnt, lists, qf, train_x, rnorm, train_y, out);
}